// Round 8
// baseline (1698.297 us; speedup 1.0000x reference)
//
#include <hip/hip_runtime.h>

typedef unsigned short ushort_t;
typedef unsigned int uint_t;
typedef unsigned long long ull_t;
typedef __attribute__((ext_vector_type(8))) short short8;
typedef __attribute__((ext_vector_type(4))) float f32x4;

#define B_ 1024
#define N_ 64
#define H_ 128
#define NT 512

// bf16 weight-image element offsets (unchanged from round 7)
#define IMG_WI 0
#define IMG_WJ 16384
#define IMG_UW 32768
#define IMG_GS 49152
#define IMG_FT 65536
#define IMG_FB 81920
#define IMG_C1 98304
#define IMG_C2 163840
#define IMG_GMT 229376
#define IMG_RW 245760
#define IMG_L 249856
#define IMG_FO 999424

__device__ __forceinline__ ushort_t f2bf(float f) {
    uint_t u = __float_as_uint(f);
    return (ushort_t)((u + 0x7fffu + ((u >> 16) & 1u)) >> 16);
}
__device__ __forceinline__ float bf2f(ushort_t u) {
    union { uint_t i; float f; } v; v.i = ((uint_t)u) << 16; return v.f;
}
__device__ __forceinline__ float siluf(float x) { return x / (1.0f + __expf(-x)); }

// LDS swizzle: 16B-chunk c of row m stored at chunk c ^ (m&7)
__device__ __forceinline__ int sidx(int m, int k) {
    return m * H_ + (((k >> 3) ^ (m & 7)) << 3) + (k & 7);
}
__device__ __forceinline__ int fragoff(int m, int ch) {
    return m * H_ + ((ch ^ (m & 7)) << 3);
}

// ========== preamble: f32 weights -> transposed bf16 images ================
extern "C" __global__ __launch_bounds__(256)
void convert_weights(const float* __restrict__ msg_W, const float* __restrict__ upd_W,
                     const float* __restrict__ gself_W, const float* __restrict__ fus_W,
                     const float* __restrict__ cb_W1, const float* __restrict__ cb_W2,
                     const float* __restrict__ gmean_W, const float* __restrict__ fo_W1,
                     ushort_t* __restrict__ wimg)
{
    const int g = blockIdx.x;
    if (g >= 244) {                      // fo_W1: 4 stages
        int st = g - 244;
        ushort_t* dst = wimg + IMG_FO + st * 4096;
        for (int e = 0; e < 16; ++e) {
            int q = threadIdx.x * 16 + e;
            int n = q >> 7, k = q & 127;
            dst[q] = f2bf(fo_W1[(size_t)k * 128 + st * 32 + n]);
        }
        return;
    }
    const int l = g / 61, r = g - l * 61;
    ushort_t* base = wimg + l * IMG_L;
    if (r == 60) {                       // rW pad image: 4 sub-stages [32f][32k]
        const float* W = msg_W + l * 35328 + 256 * 128;
        ushort_t* dst = base + IMG_RW;
        for (int e = 0; e < 16; ++e) {
            int q = threadIdx.x * 16 + e;
            int sub = q >> 10, n = (q >> 5) & 31, k = q & 31;
            dst[q] = f2bf(k < 20 ? W[(size_t)k * 128 + sub * 32 + n] : 0.0f);
        }
        return;
    }
    const float* W; int ld = 128, k0 = 0, c0, off, st;
    if      (r < 4)  { W = msg_W + l * 35328;            st = r;      off = IMG_WI;  c0 = st * 32; }
    else if (r < 8)  { W = msg_W + l * 35328;  k0 = 128; st = r - 4;  off = IMG_WJ;  c0 = st * 32; }
    else if (r < 12) { W = upd_W + l * 16384;            st = r - 8;  off = IMG_UW;  c0 = st * 32; }
    else if (r < 16) { W = gself_W + l * 16384;          st = r - 12; off = IMG_GS;  c0 = st * 32; }
    else if (r < 20) { W = fus_W + l * 32768;            st = r - 16; off = IMG_FT;  c0 = st * 32; }
    else if (r < 24) { W = fus_W + l * 32768;  k0 = 128; st = r - 20; off = IMG_FB;  c0 = st * 32; }
    else if (r < 40) { W = cb_W1 + l * 65536;  ld = 512; st = r - 24; off = IMG_C1;  c0 = st * 32; }
    else if (r < 56) { int j = (r - 40) >> 2; W = cb_W2 + l * 65536; k0 = j * 128;
                       st = r - 40; off = IMG_C2; c0 = ((r - 40) & 3) * 32; }
    else             { W = gmean_W + l * 16384;          st = r - 56; off = IMG_GMT; c0 = st * 32; }
    ushort_t* dst = base + off + st * 4096;
    for (int e = 0; e < 16; ++e) {
        int q = threadIdx.x * 16 + e;
        int n = q >> 7, k = q & 127;
        dst[q] = f2bf(W[(size_t)(k0 + k) * ld + c0 + n]);
    }
}

// ========== main fused kernel ==============================================
// LDS = 16384*2 + 4096 + 2048 + 2048 = 40960 B -> 4 blocks/CU (full 160 KiB)
struct __align__(16) Smem {
    ushort_t T1[N_ * H_];   // 16384B
    ushort_t T2[N_ * H_];   // 16384B
    float d[1024];          //  4096B  kNN: d2, then d
    ushort_t idx[1024];     //  2048B
    char u[2048];           // union: spos(768) | {part bf16 1024, hmean 512, gvec 512} | lnb(1024)
};

// one K=128 GEMM output stage s: load 4 B-frags, 4 MFMAs (16 VGPR transient)
__device__ __forceinline__ f32x4 gemm_s(const short8 a[4], const ushort_t* __restrict__ img,
                                        int s, int nl, int quad)
{
    short8 b0 = *(const short8*)(img + s * 4096 + nl * 128 + (0 * 4 + quad) * 8);
    short8 b1 = *(const short8*)(img + s * 4096 + nl * 128 + (1 * 4 + quad) * 8);
    short8 b2 = *(const short8*)(img + s * 4096 + nl * 128 + (2 * 4 + quad) * 8);
    short8 b3 = *(const short8*)(img + s * 4096 + nl * 128 + (3 * 4 + quad) * 8);
    f32x4 c = {0.f, 0.f, 0.f, 0.f};
    c = __builtin_amdgcn_mfma_f32_16x16x32_bf16(a[0], b0, c, 0, 0, 0);
    c = __builtin_amdgcn_mfma_f32_16x16x32_bf16(a[1], b1, c, 0, 0, 0);
    c = __builtin_amdgcn_mfma_f32_16x16x32_bf16(a[2], b2, c, 0, 0, 0);
    c = __builtin_amdgcn_mfma_f32_16x16x32_bf16(a[3], b3, c, 0, 0, 0);
    return c;
}
__device__ __forceinline__ void loadA(const ushort_t* __restrict__ X, int mrow, int quad, short8 a[4]) {
    #pragma unroll
    for (int kc = 0; kc < 4; ++kc) a[kc] = *(const short8*)&X[fragoff(mrow, kc * 4 + quad)];
}

extern "C" __global__ __launch_bounds__(NT, 8)
void md17_fused_kernel(
    const float* __restrict__ positions, const int* __restrict__ atomic_numbers,
    const float* __restrict__ atom_embed, const float* __restrict__ pos_W,
    const float* __restrict__ pos_b,
    const float* __restrict__ msg_b, const float* __restrict__ upd_b,
    const float* __restrict__ g_b, const float* __restrict__ fus_b,
    const float* __restrict__ ln_g, const float* __restrict__ ln_b,
    const float* __restrict__ cb_b1, const float* __restrict__ cb_b2,
    const float* __restrict__ fo_b1,
    const float* __restrict__ fo_W2, const float* __restrict__ fo_b2,
    char* __restrict__ ws, float* __restrict__ out)
{
    __shared__ Smem sm;
    const int b = blockIdx.x;
    const int tid = threadIdx.x;
    const int wave = tid >> 6, lane = tid & 63;
    const int quad = lane >> 4, l15 = lane & 15;
    const int Mt = wave >> 1;
    const int mrow = Mt * 16 + l15;
    const int nl = (wave & 1) * 16 + l15;

    const ushort_t* wimg = (const ushort_t*)ws;
    float* spos = (float*)sm.u;
    ushort_t* part = (ushort_t*)sm.u;            // [4][128] bf16 hmean partials
    float* hmean = (float*)(sm.u + 1024);
    float* gvec  = (float*)(sm.u + 1536);
    float2* lnb  = (float2*)sm.u;                // [64][2] (sum, ss)

    for (int t = tid; t < N_ * 3; t += NT) spos[t] = positions[b * N_ * 3 + t];
    __syncthreads();

    // ---- kNN (validated): wave w -> atoms w*8..w*8+7 ----
    {
        const int m = lane;
        for (int a = 0; a < 8; ++a) {
            int n = wave * 8 + a;
            float dx = __fsub_rn(spos[n * 3 + 0], spos[m * 3 + 0]);
            float dy = __fsub_rn(spos[n * 3 + 1], spos[m * 3 + 1]);
            float dz = __fsub_rn(spos[n * 3 + 2], spos[m * 3 + 2]);
            float d2 = __fadd_rn(__fadd_rn(__fmul_rn(dx, dx), __fmul_rn(dy, dy)), __fmul_rn(dz, dz));
            if (m == n) d2 = 1e30f;
            for (int k = 0; k < 16; ++k) {
                float dmin = d2;
                #pragma unroll
                for (int o = 1; o < 64; o <<= 1) dmin = fminf(dmin, __shfl_xor(dmin, o));
                ull_t mask = __ballot(d2 == dmin);
                int widx = __ffsll(mask) - 1;   // lowest index on ties (= top_k)
                if (lane == widx) d2 = 1e30f;
                if (lane == k) { sm.idx[n * 16 + k] = (ushort_t)widx; sm.d[n * 16 + k] = dmin; }
            }
        }
    }
    __syncthreads();

    // ---- d2 -> d ; embeddings -> hreg (C-layout) + T1 (bf16 A-image) ----
    for (int p = tid; p < 1024; p += NT) sm.d[p] = sqrtf(fmaxf(sm.d[p], 1e-12f));
    float hreg[4][4];
    {
        int types[4];
        #pragma unroll
        for (int r = 0; r < 4; ++r) types[r] = atomic_numbers[b * N_ + Mt * 16 + quad * 4 + r];
        #pragma unroll
        for (int s = 0; s < 4; ++s) {
            int col = s * 32 + nl;
            #pragma unroll
            for (int r = 0; r < 4; ++r) {
                int row = Mt * 16 + quad * 4 + r;
                float v;
                if (col < 32) v = atom_embed[types[r] * 32 + col];
                else {
                    int j = col - 32;
                    v = pos_b[j];
                    #pragma unroll
                    for (int c = 0; c < 3; ++c)
                        v = fmaf(spos[row * 3 + c], pos_W[c * 96 + j], v);
                }
                hreg[s][r] = v;
                sm.T1[sidx(row, col)] = f2bf(v);
            }
        }
    }
    __syncthreads();

    // rbf centers for this lane's k-dims (quad*8+j), double-rounded like np
    float ccv[8];
    #pragma unroll
    for (int j = 0; j < 8; ++j)
        ccv[j] = (float)((double)(quad * 8 + j) * (5.0 / 19.0));

    short8 a_h[4];

    #pragma unroll 1
    for (int l = 0; l < 4; ++l) {
        const ushort_t* wl = wimg + l * IMG_L;
        const float* mb  = msg_b + l * H_;
        const float* ub  = upd_b + l * H_;
        const float* gb  = g_b + l * H_;
        const float* fb  = fus_b + l * H_;
        const float* lg  = ln_g + l * H_;
        const float* lb  = ln_b + l * H_;
        const float* c1b = cb_b1 + l * 4 * H_;
        const float* c2b = cb_b2 + l * H_;

        // A: hmean partials from hreg + load a_h from T1 (h image)
        #pragma unroll
        for (int s = 0; s < 4; ++s) {
            float p = hreg[s][0] + hreg[s][1] + hreg[s][2] + hreg[s][3];
            p += __shfl_xor(p, 16);
            p += __shfl_xor(p, 32);
            if (quad == 0) part[Mt * 128 + s * 32 + nl] = f2bf(p);
        }
        loadA(sm.T1, mrow, quad, a_h);
        __syncthreads();

        // B: hmean reduce
        if (tid < H_)
            hmean[tid] = (bf2f(part[tid]) + bf2f(part[128 + tid])
                        + bf2f(part[256 + tid]) + bf2f(part[384 + tid])) * (1.0f / 64.0f);
        __syncthreads();

        // C: gvec GEMV (waves 0-1) ; WI -> T1 (+mb), WJ -> T2 (all waves)
        if (tid < H_) {
            float s = gb[tid];
            const ushort_t* wrow = wl + IMG_GMT + tid * 128;
            for (int c = 0; c < 128; c += 8) {
                short8 w = *(const short8*)(wrow + c);
                #pragma unroll
                for (int i = 0; i < 8; ++i) s = fmaf(hmean[c + i], bf2f((ushort_t)w[i]), s);
            }
            gvec[tid] = s;
        }
        #pragma unroll
        for (int s = 0; s < 4; ++s) {
            f32x4 c = gemm_s(a_h, wl + IMG_WI, s, nl, quad);
            int col = s * 32 + nl; float bv = mb[col];
            #pragma unroll
            for (int r = 0; r < 4; ++r)
                sm.T1[sidx(Mt * 16 + quad * 4 + r, col)] = f2bf(c[r] + bv);
        }
        #pragma unroll
        for (int s = 0; s < 4; ++s) {
            f32x4 c = gemm_s(a_h, wl + IMG_WJ, s, nl, quad);
            int col = s * 32 + nl;
            #pragma unroll
            for (int r = 0; r < 4; ++r)
                sm.T2[sidx(Mt * 16 + quad * 4 + r, col)] = f2bf(c[r]);
        }
        __syncthreads();

        // D: msum — wave-local, in place in T1 (reads own rows only)
        #pragma unroll 1
        for (int g = 0; g < 16; ++g) {
            int n = g * 4 + Mt;
            float ev[4]; int jv[4];
            #pragma unroll
            for (int r = 0; r < 4; ++r) {
                int k = quad * 4 + r;
                float dd = sm.d[n * 16 + k];
                jv[r] = sm.idx[n * 16 + k];
                ev[r] = (dd < 5.0f) ? 0.5f * (__cosf(0.62831853071795864769f * dd) + 1.0f) : 0.0f;
            }
            float ddm = sm.d[n * 16 + l15];
            short8 arb;
            #pragma unroll
            for (int j = 0; j < 8; ++j) {
                float t2 = ddm - ccv[j];
                float rv = __expf(-10.0f * t2 * t2);
                arb[j] = (short)((quad * 8 + j) < 20 ? f2bf(rv) : (ushort_t)0);
            }
            #pragma unroll
            for (int s = 0; s < 4; ++s) {
                short8 brw = *(const short8*)(wl + IMG_RW + s * 1024 + nl * 32 + quad * 8);
                f32x4 c = {0.f, 0.f, 0.f, 0.f};
                c = __builtin_amdgcn_mfma_f32_16x16x32_bf16(arb, brw, c, 0, 0, 0);
                int col = s * 32 + nl;
                float ai = bf2f(sm.T1[sidx(n, col)]);
                float acc = 0.f;
                #pragma unroll
                for (int r = 0; r < 4; ++r) {
                    float gm = bf2f(sm.T2[sidx(jv[r], col)]);
                    acc = fmaf(siluf(ai + gm + c[r]), ev[r], acc);
                }
                acc += __shfl_xor(acc, 16);
                acc += __shfl_xor(acc, 32);
                if (quad == 0) sm.T1[sidx(n, col)] = f2bf(acc);
            }
        }
        __syncthreads();

        // E: load a_m (msum, full rows)
        short8 a_m[4]; loadA(sm.T1, mrow, quad, a_m);
        __syncthreads();

        // F: UW(a_m) -> T2 local (hreg residual) ; GS(a_h) -> T1 glob
        #pragma unroll
        for (int s = 0; s < 4; ++s) {
            f32x4 c = gemm_s(a_m, wl + IMG_UW, s, nl, quad);
            int col = s * 32 + nl; float bv = ub[col];
            #pragma unroll
            for (int r = 0; r < 4; ++r)
                sm.T2[sidx(Mt * 16 + quad * 4 + r, col)] = f2bf(hreg[s][r] + siluf(c[r] + bv));
        }
        #pragma unroll
        for (int s = 0; s < 4; ++s) {
            f32x4 c = gemm_s(a_h, wl + IMG_GS, s, nl, quad);
            int col = s * 32 + nl; float gv = gvec[col];
            #pragma unroll
            for (int r = 0; r < 4; ++r)
                sm.T1[sidx(Mt * 16 + quad * 4 + r, col)] = f2bf(siluf(c[r] + gv));
        }
        __syncthreads();

        // G: fused = silu([local|glob]@[FT;FB]+fb) -> hreg ; LN partials
        {
            f32x4 accs[4];
            short8 a_t[4];
            loadA(sm.T2, mrow, quad, a_t);           // local
            #pragma unroll
            for (int s = 0; s < 4; ++s) accs[s] = gemm_s(a_t, wl + IMG_FT, s, nl, quad);
            loadA(sm.T1, mrow, quad, a_t);           // glob
            #pragma unroll
            for (int s = 0; s < 4; ++s) {
                f32x4 c = gemm_s(a_t, wl + IMG_FB, s, nl, quad);
                int col = s * 32 + nl; float bv = fb[col];
                #pragma unroll
                for (int r = 0; r < 4; ++r) hreg[s][r] = siluf(accs[s][r] + c[r] + bv);
            }
        }
        #pragma unroll
        for (int r = 0; r < 4; ++r) {
            float s = hreg[0][r] + hreg[1][r] + hreg[2][r] + hreg[3][r];
            float ss = hreg[0][r] * hreg[0][r] + hreg[1][r] * hreg[1][r]
                     + hreg[2][r] * hreg[2][r] + hreg[3][r] * hreg[3][r];
            #pragma unroll
            for (int o = 1; o < 16; o <<= 1) { s += __shfl_xor(s, o); ss += __shfl_xor(ss, o); }
            if (l15 == 0) lnb[(Mt * 16 + quad * 4 + r) * 2 + (wave & 1)] = make_float2(s, ss);
        }
        __syncthreads();

        // H: LN normalize -> T1 (x-hat)
        #pragma unroll
        for (int r = 0; r < 4; ++r) {
            int row = Mt * 16 + quad * 4 + r;
            float2 h0 = lnb[row * 2], h1 = lnb[row * 2 + 1];
            float mu = (h0.x + h1.x) * (1.0f / 128.0f);
            float var = (h0.y + h1.y) * (1.0f / 128.0f) - mu * mu;
            float rs = rsqrtf(var + 1e-5f);
            #pragma unroll
            for (int s = 0; s < 4; ++s) {
                int col = s * 32 + nl;
                sm.T1[sidx(row, col)] = f2bf((hreg[s][r] - mu) * rs * lg[col] + lb[col]);
            }
        }
        __syncthreads();

        // I: load a_x (x-hat)
        short8 a_x[4]; loadA(sm.T1, mrow, quad, a_x);
        __syncthreads();

        // J: Clifford MLP, 4 K-chunks; C2 accumulates directly into hreg
        #pragma unroll 1
        for (int j = 0; j < 4; ++j) {
            ushort_t* buf = (j & 1) ? sm.T1 : sm.T2;
            #pragma unroll
            for (int s = 0; s < 4; ++s) {
                f32x4 c = gemm_s(a_x, wl + IMG_C1 + j * 16384, s, nl, quad);
                int col = s * 32 + nl; float bv = c1b[j * H_ + col];
                #pragma unroll
                for (int r = 0; r < 4; ++r)
                    buf[sidx(Mt * 16 + quad * 4 + r, col)] = f2bf(siluf(c[r] + bv));
            }
            __syncthreads();
            short8 a_t[4]; loadA(buf, mrow, quad, a_t);
            #pragma unroll
            for (int s = 0; s < 4; ++s) {
                f32x4 c = gemm_s(a_t, wl + IMG_C2 + j * 16384, s, nl, quad);
                #pragma unroll
                for (int r = 0; r < 4; ++r) hreg[s][r] += c[r];
            }
            __syncthreads();
        }

        // epilogue: h_next = fused + mlp + c2b -> hreg + T1 (h image for next layer)
        #pragma unroll
        for (int s = 0; s < 4; ++s) {
            int col = s * 32 + nl; float bv = c2b[col];
            #pragma unroll
            for (int r = 0; r < 4; ++r) {
                float v = hreg[s][r] + bv;
                hreg[s][r] = v;
                sm.T1[sidx(Mt * 16 + quad * 4 + r, col)] = f2bf(v);
            }
        }
        __syncthreads();
    }

    // ---- head: FO -> T2 ; tiny GEMV -> out ----
    {
        short8 a_f[4]; loadA(sm.T1, mrow, quad, a_f);
        #pragma unroll
        for (int s = 0; s < 4; ++s) {
            f32x4 c = gemm_s(a_f, wimg + IMG_FO, s, nl, quad);
            int col = s * 32 + nl; float bv = fo_b1[col];
            #pragma unroll
            for (int r = 0; r < 4; ++r)
                sm.T2[sidx(Mt * 16 + quad * 4 + r, col)] = f2bf(siluf(c[r] + bv));
        }
    }
    __syncthreads();
    if (tid < N_ * 3) {
        int n = tid / 3, j = tid - n * 3;
        float s = fo_b2[j];
        for (int c = 0; c < H_; ++c)
            s = fmaf(bf2f(sm.T2[sidx(n, c)]), fo_W2[c * 3 + j], s);
        out[b * N_ * 3 + tid] = s;
    }
}

extern "C" void kernel_launch(void* const* d_in, const int* in_sizes, int n_in,
                              void* d_out, int out_size, void* d_ws, size_t ws_size,
                              hipStream_t stream) {
    (void)in_sizes; (void)n_in; (void)out_size; (void)ws_size;
    convert_weights<<<248, 256, 0, stream>>>(
        (const float*)d_in[5], (const float*)d_in[7], (const float*)d_in[9],
        (const float*)d_in[12], (const float*)d_in[16], (const float*)d_in[18],
        (const float*)d_in[10], (const float*)d_in[20], (ushort_t*)d_ws);
    md17_fused_kernel<<<B_, NT, 0, stream>>>(
        (const float*)d_in[0], (const int*)d_in[1],
        (const float*)d_in[2], (const float*)d_in[3], (const float*)d_in[4],
        (const float*)d_in[6], (const float*)d_in[8],
        (const float*)d_in[11], (const float*)d_in[13],
        (const float*)d_in[14], (const float*)d_in[15],
        (const float*)d_in[17], (const float*)d_in[19],
        (const float*)d_in[21],
        (const float*)d_in[22], (const float*)d_in[23],
        (char*)d_ws, (float*)d_out);
}

// Round 9
// 1584.963 us; speedup vs baseline: 1.0715x; 1.0715x over previous
//
#include <hip/hip_runtime.h>

typedef unsigned short ushort_t;
typedef unsigned int uint_t;
typedef unsigned long long ull_t;
typedef __attribute__((ext_vector_type(8))) short short8;
typedef __attribute__((ext_vector_type(4))) float f32x4;

#define B_ 1024
#define N_ 64
#define H_ 128
#define NT 512

// bf16 weight-image element offsets
#define IMG_WI 0
#define IMG_WJ 16384
#define IMG_UW 32768
#define IMG_GS 49152
#define IMG_FT 65536
#define IMG_FB 81920
#define IMG_C1 98304
#define IMG_C2 163840
#define IMG_GMT 229376
#define IMG_RW 245760
#define IMG_L 249856
#define IMG_FO 999424
#define WS_WEIGHTS (2u*1024u*1024u)
#define KNN_STRIDE 12288u

__device__ __forceinline__ ushort_t f2bf(float f) {
    uint_t u = __float_as_uint(f);
    return (ushort_t)((u + 0x7fffu + ((u >> 16) & 1u)) >> 16);
}
__device__ __forceinline__ float bf2f(ushort_t u) {
    union { uint_t i; float f; } v; v.i = ((uint_t)u) << 16; return v.f;
}
__device__ __forceinline__ float siluf(float x) { return x / (1.0f + __expf(-x)); }

// LDS swizzle: 16B-chunk c of row m stored at chunk c ^ (m&7)
__device__ __forceinline__ int sidx(int m, int k) {
    return m * H_ + (((k >> 3) ^ (m & 7)) << 3) + (k & 7);
}
__device__ __forceinline__ int fragoff(int m, int ch) {
    return m * H_ + ((ch ^ (m & 7)) << 3);
}

// ========== preamble 1: f32 weights -> transposed bf16 images ==============
extern "C" __global__ __launch_bounds__(256)
void convert_weights(const float* __restrict__ msg_W, const float* __restrict__ upd_W,
                     const float* __restrict__ gself_W, const float* __restrict__ fus_W,
                     const float* __restrict__ cb_W1, const float* __restrict__ cb_W2,
                     const float* __restrict__ gmean_W, const float* __restrict__ fo_W1,
                     ushort_t* __restrict__ wimg)
{
    const int g = blockIdx.x;
    if (g >= 244) {
        int st = g - 244;
        ushort_t* dst = wimg + IMG_FO + st * 4096;
        for (int e = 0; e < 16; ++e) {
            int q = threadIdx.x * 16 + e;
            int n = q >> 7, k = q & 127;
            dst[q] = f2bf(fo_W1[(size_t)k * 128 + st * 32 + n]);
        }
        return;
    }
    const int l = g / 61, r = g - l * 61;
    ushort_t* base = wimg + l * IMG_L;
    if (r == 60) {                       // rW pad image: 4 sub-stages [32f][32k]
        const float* W = msg_W + l * 35328 + 256 * 128;
        ushort_t* dst = base + IMG_RW;
        for (int e = 0; e < 16; ++e) {
            int q = threadIdx.x * 16 + e;
            int sub = q >> 10, n = (q >> 5) & 31, k = q & 31;
            dst[q] = f2bf(k < 20 ? W[(size_t)k * 128 + sub * 32 + n] : 0.0f);
        }
        return;
    }
    const float* W; int ld = 128, k0 = 0, c0, off, st;
    if      (r < 4)  { W = msg_W + l * 35328;            st = r;      off = IMG_WI;  c0 = st * 32; }
    else if (r < 8)  { W = msg_W + l * 35328;  k0 = 128; st = r - 4;  off = IMG_WJ;  c0 = st * 32; }
    else if (r < 12) { W = upd_W + l * 16384;            st = r - 8;  off = IMG_UW;  c0 = st * 32; }
    else if (r < 16) { W = gself_W + l * 16384;          st = r - 12; off = IMG_GS;  c0 = st * 32; }
    else if (r < 20) { W = fus_W + l * 32768;            st = r - 16; off = IMG_FT;  c0 = st * 32; }
    else if (r < 24) { W = fus_W + l * 32768;  k0 = 128; st = r - 20; off = IMG_FB;  c0 = st * 32; }
    else if (r < 40) { W = cb_W1 + l * 65536;  ld = 512; st = r - 24; off = IMG_C1;  c0 = st * 32; }
    else if (r < 56) { int j = (r - 40) >> 2; W = cb_W2 + l * 65536; k0 = j * 128;
                       st = r - 40; off = IMG_C2; c0 = ((r - 40) & 3) * 32; }
    else             { W = gmean_W + l * 16384;          st = r - 56; off = IMG_GMT; c0 = st * 32; }
    ushort_t* dst = base + off + st * 4096;
    for (int e = 0; e < 16; ++e) {
        int q = threadIdx.x * 16 + e;
        int n = q >> 7, k = q & 127;
        dst[q] = f2bf(W[(size_t)(k0 + k) * ld + c0 + n]);
    }
}

// ========== preamble 2: kNN per graph (1 wave), validated r8 logic =========
extern "C" __global__ __launch_bounds__(64)
void knn_kernel(const float* __restrict__ positions, char* __restrict__ ws)
{
    const int b = blockIdx.x, lane = threadIdx.x;
    float px = positions[b * 192 + lane * 3 + 0];
    float py = positions[b * 192 + lane * 3 + 1];
    float pz = positions[b * 192 + lane * 3 + 2];
    float* kd = (float*)(ws + WS_WEIGHTS + (size_t)b * KNN_STRIDE);
    float* ke = kd + 1024;
    ushort_t* ki = (ushort_t*)(ke + 1024);
    for (int n = 0; n < 64; ++n) {
        float dx = __fsub_rn(__shfl(px, n), px);
        float dy = __fsub_rn(__shfl(py, n), py);
        float dz = __fsub_rn(__shfl(pz, n), pz);
        float d2 = __fadd_rn(__fadd_rn(__fmul_rn(dx, dx), __fmul_rn(dy, dy)), __fmul_rn(dz, dz));
        if (lane == n) d2 = 1e30f;
        float sd = 0.f; int si = 0;
        for (int k = 0; k < 16; ++k) {
            float dmin = d2;
            #pragma unroll
            for (int o = 1; o < 64; o <<= 1) dmin = fminf(dmin, __shfl_xor(dmin, o));
            ull_t mask = __ballot(d2 == dmin);
            int widx = __ffsll(mask) - 1;       // lowest index on ties (= top_k)
            if (lane == widx) d2 = 1e30f;
            if (lane == k) { si = widx; sd = dmin; }
        }
        if (lane < 16) {
            float dd = sqrtf(fmaxf(sd, 1e-12f));
            kd[n * 16 + lane] = dd;
            ke[n * 16 + lane] = (dd < 5.0f) ? 0.5f * (__cosf(0.62831853071795864769f * dd) + 1.0f) : 0.0f;
            ki[n * 16 + lane] = (ushort_t)si;
        }
    }
}

// ========== main fused kernel ==============================================
// LDS: 16384*2 + 33792 + 4096 + 4096 + 2048 + 2048 = 78848 B -> 2 blocks/CU
#define HFS 132   // padded f32 row stride
struct __align__(16) Smem {
    ushort_t T1[N_ * H_];   // 16384B
    ushort_t T2[N_ * H_];   // 16384B
    float Hf[N_ * HFS];     // 33792B  f32 residual stream
    float d[1024];          //  4096B
    float env[1024];        //  4096B
    ushort_t idx[1024];     //  2048B
    char u[2048];           // union: spos | {part bf16, hmean, gvec} | lnb
};

__device__ __forceinline__ f32x4 gemm_s(const short8 a[4], const ushort_t* __restrict__ img,
                                        int s, int nl, int quad)
{
    short8 b0 = *(const short8*)(img + s * 4096 + nl * 128 + (0 * 4 + quad) * 8);
    short8 b1 = *(const short8*)(img + s * 4096 + nl * 128 + (1 * 4 + quad) * 8);
    short8 b2 = *(const short8*)(img + s * 4096 + nl * 128 + (2 * 4 + quad) * 8);
    short8 b3 = *(const short8*)(img + s * 4096 + nl * 128 + (3 * 4 + quad) * 8);
    f32x4 c = {0.f, 0.f, 0.f, 0.f};
    c = __builtin_amdgcn_mfma_f32_16x16x32_bf16(a[0], b0, c, 0, 0, 0);
    c = __builtin_amdgcn_mfma_f32_16x16x32_bf16(a[1], b1, c, 0, 0, 0);
    c = __builtin_amdgcn_mfma_f32_16x16x32_bf16(a[2], b2, c, 0, 0, 0);
    c = __builtin_amdgcn_mfma_f32_16x16x32_bf16(a[3], b3, c, 0, 0, 0);
    return c;
}
__device__ __forceinline__ void loadA(const ushort_t* __restrict__ X, int mrow, int quad, short8 a[4]) {
    #pragma unroll
    for (int kc = 0; kc < 4; ++kc) a[kc] = *(const short8*)&X[fragoff(mrow, kc * 4 + quad)];
}
// rebuild bf16 A-fragment from f32 Hf
__device__ __forceinline__ void buildA(const float* __restrict__ Hf, int mrow, int quad, short8 a[4]) {
    #pragma unroll
    for (int kc = 0; kc < 4; ++kc) {
        const float* p = Hf + mrow * HFS + (kc * 4 + quad) * 8;
        float4 u0 = *(const float4*)p;
        float4 u1 = *(const float4*)(p + 4);
        short8 v;
        v[0] = (short)f2bf(u0.x); v[1] = (short)f2bf(u0.y);
        v[2] = (short)f2bf(u0.z); v[3] = (short)f2bf(u0.w);
        v[4] = (short)f2bf(u1.x); v[5] = (short)f2bf(u1.y);
        v[6] = (short)f2bf(u1.z); v[7] = (short)f2bf(u1.w);
        a[kc] = v;
    }
}

extern "C" __global__ __launch_bounds__(NT, 4)
void md17_fused_kernel(
    const float* __restrict__ positions, const int* __restrict__ atomic_numbers,
    const float* __restrict__ atom_embed, const float* __restrict__ pos_W,
    const float* __restrict__ pos_b,
    const float* __restrict__ msg_b, const float* __restrict__ upd_b,
    const float* __restrict__ g_b, const float* __restrict__ fus_b,
    const float* __restrict__ ln_g, const float* __restrict__ ln_b,
    const float* __restrict__ cb_b1, const float* __restrict__ cb_b2,
    const float* __restrict__ fo_b1,
    const float* __restrict__ fo_W2, const float* __restrict__ fo_b2,
    char* __restrict__ ws, float* __restrict__ out)
{
    __shared__ Smem sm;
    const int b = blockIdx.x;
    const int tid = threadIdx.x;
    const int wave = tid >> 6, lane = tid & 63;
    const int quad = lane >> 4, l15 = lane & 15;
    const int Mt = wave >> 1;
    const int mrow = Mt * 16 + l15;
    const int nl = (wave & 1) * 16 + l15;

    const ushort_t* wimg = (const ushort_t*)ws;
    float* spos = (float*)sm.u;
    ushort_t* part = (ushort_t*)sm.u;        // [4][128] bf16 hmean partials
    float* hmean = (float*)(sm.u + 1024);
    float* gvec  = (float*)(sm.u + 1536);
    float2* lnb  = (float2*)sm.u;            // [64][2] (sum, ss)

    // ---- load kNN blob + positions ----
    {
        const char* kb = ws + WS_WEIGHTS + (size_t)b * KNN_STRIDE;
        const float* kd = (const float*)kb;
        const float* ke = (const float*)(kb + 4096);
        const uint_t* ki = (const uint_t*)(kb + 8192);
        for (int t = tid; t < 1024; t += NT) { sm.d[t] = kd[t]; sm.env[t] = ke[t]; }
        ((uint_t*)sm.idx)[tid] = ki[tid];
        if (tid < 192) spos[tid] = positions[b * 192 + tid];
    }
    __syncthreads();

    // ---- embeddings -> Hf (f32) + T1 (bf16 image) ----
    for (int t = tid; t < N_ * H_; t += NT) {
        int n = t >> 7, f = t & 127;
        float v;
        if (f < 32) {
            v = atom_embed[atomic_numbers[b * N_ + n] * 32 + f];
        } else {
            int j = f - 32;
            v = pos_b[j];
            #pragma unroll
            for (int c = 0; c < 3; ++c)
                v = fmaf(spos[n * 3 + c], pos_W[c * 96 + j], v);
        }
        sm.Hf[n * HFS + f] = v;
        sm.T1[sidx(n, f)] = f2bf(v);
    }
    __syncthreads();

    // rbf centers (lane k-dims quad*8+j), double-rounded like np
    float ccv[8];
    #pragma unroll
    for (int j = 0; j < 8; ++j)
        ccv[j] = (float)((double)(quad * 8 + j) * (5.0 / 19.0));

    #pragma unroll 1
    for (int l = 0; l < 4; ++l) {
        const ushort_t* wl = wimg + l * IMG_L;
        const float* mb  = msg_b + l * H_;
        const float* ub  = upd_b + l * H_;
        const float* gb  = g_b + l * H_;
        const float* fb  = fus_b + l * H_;
        const float* lg  = ln_g + l * H_;
        const float* lb  = ln_b + l * H_;
        const float* c1b = cb_b1 + l * 4 * H_;
        const float* c2b = cb_b2 + l * H_;

        // A: hmean partials from Hf ; load a_h
        short8 a_h[4];
        #pragma unroll
        for (int s = 0; s < 4; ++s) {
            int col = s * 32 + nl;
            const float* hp = sm.Hf + (Mt * 16 + quad * 4) * HFS + col;
            float p = hp[0] + hp[HFS] + hp[2 * HFS] + hp[3 * HFS];
            p += __shfl_xor(p, 16);
            p += __shfl_xor(p, 32);
            if (quad == 0) part[Mt * 128 + col] = f2bf(p);
        }
        loadA(sm.T1, mrow, quad, a_h);
        __syncthreads();

        // B: hmean reduce
        if (tid < H_)
            hmean[tid] = (bf2f(part[tid]) + bf2f(part[128 + tid])
                        + bf2f(part[256 + tid]) + bf2f(part[384 + tid])) * (1.0f / 64.0f);
        __syncthreads();

        // C: gvec GEMV ; WI -> T1 (+mb) ; WJ -> T2
        if (tid < H_) {
            float s = gb[tid];
            const ushort_t* wrow = wl + IMG_GMT + tid * 128;
            for (int c = 0; c < 128; c += 8) {
                short8 w = *(const short8*)(wrow + c);
                #pragma unroll
                for (int i = 0; i < 8; ++i) s = fmaf(hmean[c + i], bf2f((ushort_t)w[i]), s);
            }
            gvec[tid] = s;
        }
        #pragma unroll
        for (int s = 0; s < 4; ++s) {
            f32x4 c = gemm_s(a_h, wl + IMG_WI, s, nl, quad);
            int col = s * 32 + nl; float bv = mb[col];
            #pragma unroll
            for (int r = 0; r < 4; ++r)
                sm.T1[sidx(Mt * 16 + quad * 4 + r, col)] = f2bf(c[r] + bv);
        }
        #pragma unroll
        for (int s = 0; s < 4; ++s) {
            f32x4 c = gemm_s(a_h, wl + IMG_WJ, s, nl, quad);
            int col = s * 32 + nl;
            #pragma unroll
            for (int r = 0; r < 4; ++r)
                sm.T2[sidx(Mt * 16 + quad * 4 + r, col)] = f2bf(c[r]);
        }
        __syncthreads();

        // D: msum — wave-local, in place in T1
        #pragma unroll 1
        for (int g = 0; g < 16; ++g) {
            int n = g * 4 + Mt;
            float ddm = sm.d[n * 16 + l15];
            short8 arb;
            #pragma unroll
            for (int j = 0; j < 8; ++j) {
                float t2 = ddm - ccv[j];
                float rv = __expf(-10.0f * t2 * t2);
                arb[j] = (short)((quad * 8 + j) < 20 ? f2bf(rv) : (ushort_t)0);
            }
            #pragma unroll
            for (int s = 0; s < 4; ++s) {
                short8 brw = *(const short8*)(wl + IMG_RW + s * 1024 + nl * 32 + quad * 8);
                f32x4 c = {0.f, 0.f, 0.f, 0.f};
                c = __builtin_amdgcn_mfma_f32_16x16x32_bf16(arb, brw, c, 0, 0, 0);
                int col = s * 32 + nl;
                float ai = bf2f(sm.T1[sidx(n, col)]);
                float acc = 0.f;
                #pragma unroll
                for (int r = 0; r < 4; ++r) {
                    int k = quad * 4 + r;
                    int j = sm.idx[n * 16 + k];
                    float e = sm.env[n * 16 + k];
                    float gm = bf2f(sm.T2[sidx(j, col)]);
                    acc = fmaf(siluf(ai + gm + c[r]), e, acc);
                }
                acc += __shfl_xor(acc, 16);
                acc += __shfl_xor(acc, 32);
                if (quad == 0) sm.T1[sidx(n, col)] = f2bf(acc);
            }
        }
        __syncthreads();

        // E: load a_m (msum)
        short8 a_m[4]; loadA(sm.T1, mrow, quad, a_m);
        __syncthreads();

        // F: UW(a_m)+Hf -> T2 local ; GS(rebuilt h)+gvec -> T1 glob
        #pragma unroll
        for (int s = 0; s < 4; ++s) {
            f32x4 c = gemm_s(a_m, wl + IMG_UW, s, nl, quad);
            int col = s * 32 + nl; float bv = ub[col];
            #pragma unroll
            for (int r = 0; r < 4; ++r) {
                int row = Mt * 16 + quad * 4 + r;
                sm.T2[sidx(row, col)] = f2bf(sm.Hf[row * HFS + col] + siluf(c[r] + bv));
            }
        }
        {
            short8 a_hh[4]; buildA(sm.Hf, mrow, quad, a_hh);
            #pragma unroll
            for (int s = 0; s < 4; ++s) {
                f32x4 c = gemm_s(a_hh, wl + IMG_GS, s, nl, quad);
                int col = s * 32 + nl; float gv = gvec[col];
                #pragma unroll
                for (int r = 0; r < 4; ++r)
                    sm.T1[sidx(Mt * 16 + quad * 4 + r, col)] = f2bf(siluf(c[r] + gv));
            }
        }
        __syncthreads();

        // G: fused = silu([local|glob]@[FT;FB]+fb) -> Hf ; LN partials
        {
            f32x4 accs[4];
            short8 a_t[4];
            loadA(sm.T2, mrow, quad, a_t);           // local
            #pragma unroll
            for (int s = 0; s < 4; ++s) accs[s] = gemm_s(a_t, wl + IMG_FT, s, nl, quad);
            loadA(sm.T1, mrow, quad, a_t);           // glob
            float sr0 = 0.f, sr1 = 0.f, sr2 = 0.f, sr3 = 0.f;
            float qr0 = 0.f, qr1 = 0.f, qr2 = 0.f, qr3 = 0.f;
            #pragma unroll
            for (int s = 0; s < 4; ++s) {
                f32x4 c = gemm_s(a_t, wl + IMG_FB, s, nl, quad);
                int col = s * 32 + nl; float bv = fb[col];
                float v0 = siluf(accs[s][0] + c[0] + bv);
                float v1 = siluf(accs[s][1] + c[1] + bv);
                float v2 = siluf(accs[s][2] + c[2] + bv);
                float v3 = siluf(accs[s][3] + c[3] + bv);
                int rb = (Mt * 16 + quad * 4) * HFS + col;
                sm.Hf[rb] = v0; sm.Hf[rb + HFS] = v1;
                sm.Hf[rb + 2 * HFS] = v2; sm.Hf[rb + 3 * HFS] = v3;
                sr0 += v0; sr1 += v1; sr2 += v2; sr3 += v3;
                qr0 += v0 * v0; qr1 += v1 * v1; qr2 += v2 * v2; qr3 += v3 * v3;
            }
            #pragma unroll
            for (int o = 1; o < 16; o <<= 1) {
                sr0 += __shfl_xor(sr0, o); qr0 += __shfl_xor(qr0, o);
                sr1 += __shfl_xor(sr1, o); qr1 += __shfl_xor(qr1, o);
                sr2 += __shfl_xor(sr2, o); qr2 += __shfl_xor(qr2, o);
                sr3 += __shfl_xor(sr3, o); qr3 += __shfl_xor(qr3, o);
            }
            if (l15 == 0) {
                int base = (Mt * 16 + quad * 4) * 2 + (wave & 1);
                lnb[base]     = make_float2(sr0, qr0);
                lnb[base + 2] = make_float2(sr1, qr1);
                lnb[base + 4] = make_float2(sr2, qr2);
                lnb[base + 6] = make_float2(sr3, qr3);
            }
        }
        __syncthreads();

        // H: LN normalize (from Hf) -> T1 (x-hat)
        #pragma unroll
        for (int r = 0; r < 4; ++r) {
            int row = Mt * 16 + quad * 4 + r;
            float2 h0 = lnb[row * 2], h1 = lnb[row * 2 + 1];
            float mu = (h0.x + h1.x) * (1.0f / 128.0f);
            float var = (h0.y + h1.y) * (1.0f / 128.0f) - mu * mu;
            float rs = rsqrtf(var + 1e-5f);
            #pragma unroll
            for (int s = 0; s < 4; ++s) {
                int col = s * 32 + nl;
                sm.T1[sidx(row, col)] = f2bf((sm.Hf[row * HFS + col] - mu) * rs * lg[col] + lb[col]);
            }
        }
        __syncthreads();

        // I: load a_x (x-hat)
        short8 a_x[4]; loadA(sm.T1, mrow, quad, a_x);
        __syncthreads();

        // J: Clifford MLP, 4 K-chunks; C2 accumulates into Hf
        #pragma unroll 1
        for (int j = 0; j < 4; ++j) {
            ushort_t* buf = (j & 1) ? sm.T1 : sm.T2;
            #pragma unroll
            for (int s = 0; s < 4; ++s) {
                f32x4 c = gemm_s(a_x, wl + IMG_C1 + j * 16384, s, nl, quad);
                int col = s * 32 + nl; float bv = c1b[j * H_ + col];
                #pragma unroll
                for (int r = 0; r < 4; ++r)
                    buf[sidx(Mt * 16 + quad * 4 + r, col)] = f2bf(siluf(c[r] + bv));
            }
            __syncthreads();
            short8 a_t[4]; loadA(buf, mrow, quad, a_t);
            #pragma unroll
            for (int s = 0; s < 4; ++s) {
                f32x4 c = gemm_s(a_t, wl + IMG_C2 + j * 16384, s, nl, quad);
                int col = s * 32 + nl;
                #pragma unroll
                for (int r = 0; r < 4; ++r)
                    sm.Hf[(Mt * 16 + quad * 4 + r) * HFS + col] += c[r];
            }
        }
        __syncthreads();

        // K: epilogue: Hf += c2b ; write bf16 image -> T1
        #pragma unroll
        for (int s = 0; s < 4; ++s) {
            int col = s * 32 + nl; float bv = c2b[col];
            #pragma unroll
            for (int r = 0; r < 4; ++r) {
                int row = Mt * 16 + quad * 4 + r;
                float v = sm.Hf[row * HFS + col] + bv;
                sm.Hf[row * HFS + col] = v;
                sm.T1[sidx(row, col)] = f2bf(v);
            }
        }
        __syncthreads();
    }

    // ---- head ----
    {
        short8 a_f[4]; loadA(sm.T1, mrow, quad, a_f);
        #pragma unroll
        for (int s = 0; s < 4; ++s) {
            f32x4 c = gemm_s(a_f, wimg + IMG_FO, s, nl, quad);
            int col = s * 32 + nl; float bv = fo_b1[col];
            #pragma unroll
            for (int r = 0; r < 4; ++r)
                sm.T2[sidx(Mt * 16 + quad * 4 + r, col)] = f2bf(siluf(c[r] + bv));
        }
    }
    __syncthreads();
    if (tid < N_ * 3) {
        int n = tid / 3, j = tid - n * 3;
        float s = fo_b2[j];
        for (int c = 0; c < H_; ++c)
            s = fmaf(bf2f(sm.T2[sidx(n, c)]), fo_W2[c * 3 + j], s);
        out[b * N_ * 3 + tid] = s;
    }
}

extern "C" void kernel_launch(void* const* d_in, const int* in_sizes, int n_in,
                              void* d_out, int out_size, void* d_ws, size_t ws_size,
                              hipStream_t stream) {
    (void)in_sizes; (void)n_in; (void)out_size; (void)ws_size;
    convert_weights<<<248, 256, 0, stream>>>(
        (const float*)d_in[5], (const float*)d_in[7], (const float*)d_in[9],
        (const float*)d_in[12], (const float*)d_in[16], (const float*)d_in[18],
        (const float*)d_in[10], (const float*)d_in[20], (ushort_t*)d_ws);
    knn_kernel<<<B_, 64, 0, stream>>>((const float*)d_in[0], (char*)d_ws);
    md17_fused_kernel<<<B_, NT, 0, stream>>>(
        (const float*)d_in[0], (const int*)d_in[1],
        (const float*)d_in[2], (const float*)d_in[3], (const float*)d_in[4],
        (const float*)d_in[6], (const float*)d_in[8],
        (const float*)d_in[11], (const float*)d_in[13],
        (const float*)d_in[14], (const float*)d_in[15],
        (const float*)d_in[17], (const float*)d_in[19],
        (const float*)d_in[21],
        (const float*)d_in[22], (const float*)d_in[23],
        (char*)d_ws, (float*)d_out);
}

// Round 10
// 1489.552 us; speedup vs baseline: 1.1401x; 1.0641x over previous
//
#include <hip/hip_runtime.h>

typedef unsigned short ushort_t;
typedef unsigned int uint_t;
typedef unsigned long long ull_t;
typedef __attribute__((ext_vector_type(8))) short short8;
typedef __attribute__((ext_vector_type(4))) float f32x4;

#define B_ 1024
#define N_ 64
#define H_ 128
#define NT 512

// bf16 weight-image element offsets
#define IMG_WI 0
#define IMG_WJ 16384
#define IMG_UW 32768
#define IMG_GS 49152
#define IMG_FT 65536
#define IMG_FB 81920
#define IMG_C1 98304
#define IMG_C2 163840
#define IMG_GMT 229376
#define IMG_RW 245760
#define IMG_L 249856
#define IMG_FO 999424
#define WS_WEIGHTS (2u*1024u*1024u)
#define KNN_STRIDE 12288u

__device__ __forceinline__ ushort_t f2bf(float f) {
    uint_t u = __float_as_uint(f);
    return (ushort_t)((u + 0x7fffu + ((u >> 16) & 1u)) >> 16);
}
__device__ __forceinline__ float bf2f(ushort_t u) {
    union { uint_t i; float f; } v; v.i = ((uint_t)u) << 16; return v.f;
}
__device__ __forceinline__ float siluf(float x) { return x / (1.0f + __expf(-x)); }

// LDS swizzle: 16B-chunk c of row m stored at chunk c ^ (m&7)
__device__ __forceinline__ int sidx(int m, int k) {
    return m * H_ + (((k >> 3) ^ (m & 7)) << 3) + (k & 7);
}
__device__ __forceinline__ int fragoff(int m, int ch) {
    return m * H_ + ((ch ^ (m & 7)) << 3);
}

// ========== preamble 1: f32 weights -> transposed bf16 images ==============
extern "C" __global__ __launch_bounds__(256)
void convert_weights(const float* __restrict__ msg_W, const float* __restrict__ upd_W,
                     const float* __restrict__ gself_W, const float* __restrict__ fus_W,
                     const float* __restrict__ cb_W1, const float* __restrict__ cb_W2,
                     const float* __restrict__ gmean_W, const float* __restrict__ fo_W1,
                     ushort_t* __restrict__ wimg)
{
    const int g = blockIdx.x;
    if (g >= 244) {
        int st = g - 244;
        ushort_t* dst = wimg + IMG_FO + st * 4096;
        for (int e = 0; e < 16; ++e) {
            int q = threadIdx.x * 16 + e;
            int n = q >> 7, k = q & 127;
            dst[q] = f2bf(fo_W1[(size_t)k * 128 + st * 32 + n]);
        }
        return;
    }
    const int l = g / 61, r = g - l * 61;
    ushort_t* base = wimg + l * IMG_L;
    if (r == 60) {                       // rW pad image: 4 sub-stages [32f][32k]
        const float* W = msg_W + l * 35328 + 256 * 128;
        ushort_t* dst = base + IMG_RW;
        for (int e = 0; e < 16; ++e) {
            int q = threadIdx.x * 16 + e;
            int sub = q >> 10, n = (q >> 5) & 31, k = q & 31;
            dst[q] = f2bf(k < 20 ? W[(size_t)k * 128 + sub * 32 + n] : 0.0f);
        }
        return;
    }
    const float* W; int ld = 128, k0 = 0, c0, off, st;
    if      (r < 4)  { W = msg_W + l * 35328;            st = r;      off = IMG_WI;  c0 = st * 32; }
    else if (r < 8)  { W = msg_W + l * 35328;  k0 = 128; st = r - 4;  off = IMG_WJ;  c0 = st * 32; }
    else if (r < 12) { W = upd_W + l * 16384;            st = r - 8;  off = IMG_UW;  c0 = st * 32; }
    else if (r < 16) { W = gself_W + l * 16384;          st = r - 12; off = IMG_GS;  c0 = st * 32; }
    else if (r < 20) { W = fus_W + l * 32768;            st = r - 16; off = IMG_FT;  c0 = st * 32; }
    else if (r < 24) { W = fus_W + l * 32768;  k0 = 128; st = r - 20; off = IMG_FB;  c0 = st * 32; }
    else if (r < 40) { W = cb_W1 + l * 65536;  ld = 512; st = r - 24; off = IMG_C1;  c0 = st * 32; }
    else if (r < 56) { int j = (r - 40) >> 2; W = cb_W2 + l * 65536; k0 = j * 128;
                       st = r - 40; off = IMG_C2; c0 = ((r - 40) & 3) * 32; }
    else             { W = gmean_W + l * 16384;          st = r - 56; off = IMG_GMT; c0 = st * 32; }
    ushort_t* dst = base + off + st * 4096;
    for (int e = 0; e < 16; ++e) {
        int q = threadIdx.x * 16 + e;
        int n = q >> 7, k = q & 127;
        dst[q] = f2bf(W[(size_t)(k0 + k) * ld + c0 + n]);
    }
}

// ========== preamble 2: kNN per graph (1 wave), validated logic ============
extern "C" __global__ __launch_bounds__(64)
void knn_kernel(const float* __restrict__ positions, char* __restrict__ ws)
{
    const int b = blockIdx.x, lane = threadIdx.x;
    float px = positions[b * 192 + lane * 3 + 0];
    float py = positions[b * 192 + lane * 3 + 1];
    float pz = positions[b * 192 + lane * 3 + 2];
    float* kd = (float*)(ws + WS_WEIGHTS + (size_t)b * KNN_STRIDE);
    float* ke = kd + 1024;
    ushort_t* ki = (ushort_t*)(ke + 1024);
    for (int n = 0; n < 64; ++n) {
        float dx = __fsub_rn(__shfl(px, n), px);
        float dy = __fsub_rn(__shfl(py, n), py);
        float dz = __fsub_rn(__shfl(pz, n), pz);
        float d2 = __fadd_rn(__fadd_rn(__fmul_rn(dx, dx), __fmul_rn(dy, dy)), __fmul_rn(dz, dz));
        if (lane == n) d2 = 1e30f;
        float sd = 0.f; int si = 0;
        for (int k = 0; k < 16; ++k) {
            float dmin = d2;
            #pragma unroll
            for (int o = 1; o < 64; o <<= 1) dmin = fminf(dmin, __shfl_xor(dmin, o));
            ull_t mask = __ballot(d2 == dmin);
            int widx = __ffsll(mask) - 1;       // lowest index on ties (= top_k)
            if (lane == widx) d2 = 1e30f;
            if (lane == k) { si = widx; sd = dmin; }
        }
        if (lane < 16) {
            float dd = sqrtf(fmaxf(sd, 1e-12f));
            kd[n * 16 + lane] = dd;
            ke[n * 16 + lane] = (dd < 5.0f) ? 0.5f * (__cosf(0.62831853071795864769f * dd) + 1.0f) : 0.0f;
            ki[n * 16 + lane] = (ushort_t)si;
        }
    }
}

// ========== main fused kernel ==============================================
// LDS: 16384*2 + 33792 + 4096 + 4096 + 2048 + 2048 = 78848 B -> 2 blocks/CU
#define HFS 132   // padded f32 row stride
struct __align__(16) Smem {
    ushort_t T1[N_ * H_];   // 16384B
    ushort_t T2[N_ * H_];   // 16384B
    float Hf[N_ * HFS];     // 33792B  f32 residual stream
    float d[1024];          //  4096B
    float env[1024];        //  4096B
    ushort_t idx[1024];     //  2048B
    char u[2048];           // union: spos | {part bf16, hmean, gvec} | lnb
};

__device__ __forceinline__ f32x4 gemm_s(const short8 a[4], const ushort_t* __restrict__ img,
                                        int s, int nl, int quad)
{
    short8 b0 = *(const short8*)(img + s * 4096 + nl * 128 + (0 * 4 + quad) * 8);
    short8 b1 = *(const short8*)(img + s * 4096 + nl * 128 + (1 * 4 + quad) * 8);
    short8 b2 = *(const short8*)(img + s * 4096 + nl * 128 + (2 * 4 + quad) * 8);
    short8 b3 = *(const short8*)(img + s * 4096 + nl * 128 + (3 * 4 + quad) * 8);
    f32x4 c = {0.f, 0.f, 0.f, 0.f};
    c = __builtin_amdgcn_mfma_f32_16x16x32_bf16(a[0], b0, c, 0, 0, 0);
    c = __builtin_amdgcn_mfma_f32_16x16x32_bf16(a[1], b1, c, 0, 0, 0);
    c = __builtin_amdgcn_mfma_f32_16x16x32_bf16(a[2], b2, c, 0, 0, 0);
    c = __builtin_amdgcn_mfma_f32_16x16x32_bf16(a[3], b3, c, 0, 0, 0);
    return c;
}
__device__ __forceinline__ f32x4 gemm_s_acc(const short8 a[4], const ushort_t* __restrict__ img,
                                            int s, int nl, int quad, f32x4 c)
{
    short8 b0 = *(const short8*)(img + s * 4096 + nl * 128 + (0 * 4 + quad) * 8);
    short8 b1 = *(const short8*)(img + s * 4096 + nl * 128 + (1 * 4 + quad) * 8);
    short8 b2 = *(const short8*)(img + s * 4096 + nl * 128 + (2 * 4 + quad) * 8);
    short8 b3 = *(const short8*)(img + s * 4096 + nl * 128 + (3 * 4 + quad) * 8);
    c = __builtin_amdgcn_mfma_f32_16x16x32_bf16(a[0], b0, c, 0, 0, 0);
    c = __builtin_amdgcn_mfma_f32_16x16x32_bf16(a[1], b1, c, 0, 0, 0);
    c = __builtin_amdgcn_mfma_f32_16x16x32_bf16(a[2], b2, c, 0, 0, 0);
    c = __builtin_amdgcn_mfma_f32_16x16x32_bf16(a[3], b3, c, 0, 0, 0);
    return c;
}
__device__ __forceinline__ void loadA(const ushort_t* __restrict__ X, int mrow, int quad, short8 a[4]) {
    #pragma unroll
    for (int kc = 0; kc < 4; ++kc) a[kc] = *(const short8*)&X[fragoff(mrow, kc * 4 + quad)];
}
// rebuild bf16 A-fragment from f32 Hf
__device__ __forceinline__ void buildA(const float* __restrict__ Hf, int mrow, int quad, short8 a[4]) {
    #pragma unroll
    for (int kc = 0; kc < 4; ++kc) {
        const float* p = Hf + mrow * HFS + (kc * 4 + quad) * 8;
        float4 u0 = *(const float4*)p;
        float4 u1 = *(const float4*)(p + 4);
        short8 v;
        v[0] = (short)f2bf(u0.x); v[1] = (short)f2bf(u0.y);
        v[2] = (short)f2bf(u0.z); v[3] = (short)f2bf(u0.w);
        v[4] = (short)f2bf(u1.x); v[5] = (short)f2bf(u1.y);
        v[6] = (short)f2bf(u1.z); v[7] = (short)f2bf(u1.w);
        a[kc] = v;
    }
}

extern "C" __global__ __launch_bounds__(NT, 4)
void md17_fused_kernel(
    const float* __restrict__ positions, const int* __restrict__ atomic_numbers,
    const float* __restrict__ atom_embed, const float* __restrict__ pos_W,
    const float* __restrict__ pos_b,
    const float* __restrict__ msg_b, const float* __restrict__ upd_b,
    const float* __restrict__ g_b, const float* __restrict__ fus_b,
    const float* __restrict__ ln_g, const float* __restrict__ ln_b,
    const float* __restrict__ cb_b1, const float* __restrict__ cb_b2,
    const float* __restrict__ fo_b1,
    const float* __restrict__ fo_W2, const float* __restrict__ fo_b2,
    char* __restrict__ ws, float* __restrict__ out)
{
    __shared__ Smem sm;
    const int b = blockIdx.x;
    const int tid = threadIdx.x;
    const int wave = tid >> 6, lane = tid & 63;
    const int quad = lane >> 4, l15 = lane & 15;
    const int Mt = wave >> 1;
    const int mrow = Mt * 16 + l15;
    const int nl = (wave & 1) * 16 + l15;

    const ushort_t* wimg = (const ushort_t*)ws;
    float* spos = (float*)sm.u;
    ushort_t* part = (ushort_t*)sm.u;        // [4][128] bf16 hmean partials
    float* hmean = (float*)(sm.u + 1024);
    float* gvec  = (float*)(sm.u + 1536);
    float2* lnb  = (float2*)sm.u;            // [64][2] (sum, ss)

    // ---- load kNN blob + positions ----
    {
        const char* kb = ws + WS_WEIGHTS + (size_t)b * KNN_STRIDE;
        const float* kd = (const float*)kb;
        const float* ke = (const float*)(kb + 4096);
        const uint_t* ki = (const uint_t*)(kb + 8192);
        for (int t = tid; t < 1024; t += NT) { sm.d[t] = kd[t]; sm.env[t] = ke[t]; }
        ((uint_t*)sm.idx)[tid] = ki[tid];
        if (tid < 192) spos[tid] = positions[b * 192 + tid];
    }
    __syncthreads();

    // ---- embeddings -> Hf (f32) + T1 (bf16 image) ----
    for (int t = tid; t < N_ * H_; t += NT) {
        int n = t >> 7, f = t & 127;
        float v;
        if (f < 32) {
            v = atom_embed[atomic_numbers[b * N_ + n] * 32 + f];
        } else {
            int j = f - 32;
            v = pos_b[j];
            #pragma unroll
            for (int c = 0; c < 3; ++c)
                v = fmaf(spos[n * 3 + c], pos_W[c * 96 + j], v);
        }
        sm.Hf[n * HFS + f] = v;
        sm.T1[sidx(n, f)] = f2bf(v);
    }
    __syncthreads();

    #pragma unroll 1
    for (int l = 0; l < 4; ++l) {
        const ushort_t* wl = wimg + l * IMG_L;
        const float* mb  = msg_b + l * H_;
        const float* ub  = upd_b + l * H_;
        const float* gb  = g_b + l * H_;
        const float* fb  = fus_b + l * H_;
        const float* lg  = ln_g + l * H_;
        const float* lb  = ln_b + l * H_;
        const float* c1b = cb_b1 + l * 4 * H_;
        const float* c2b = cb_b2 + l * H_;

        // A: hmean partials from Hf ; load a_h
        short8 a_h[4];
        #pragma unroll
        for (int s = 0; s < 4; ++s) {
            int col = s * 32 + nl;
            const float* hp = sm.Hf + (Mt * 16 + quad * 4) * HFS + col;
            float p = hp[0] + hp[HFS] + hp[2 * HFS] + hp[3 * HFS];
            p += __shfl_xor(p, 16);
            p += __shfl_xor(p, 32);
            if (quad == 0) part[Mt * 128 + col] = f2bf(p);
        }
        loadA(sm.T1, mrow, quad, a_h);
        __syncthreads();

        // B: hmean reduce
        if (tid < H_)
            hmean[tid] = (bf2f(part[tid]) + bf2f(part[128 + tid])
                        + bf2f(part[256 + tid]) + bf2f(part[384 + tid])) * (1.0f / 64.0f);
        __syncthreads();

        // C: gvec GEMV ; WI -> T1 (+mb) ; WJ -> T2
        if (tid < H_) {
            float s = gb[tid];
            const ushort_t* wrow = wl + IMG_GMT + tid * 128;
            for (int c = 0; c < 128; c += 8) {
                short8 w = *(const short8*)(wrow + c);
                #pragma unroll
                for (int i = 0; i < 8; ++i) s = fmaf(hmean[c + i], bf2f((ushort_t)w[i]), s);
            }
            gvec[tid] = s;
        }
        #pragma unroll
        for (int s = 0; s < 4; ++s) {
            f32x4 c = gemm_s(a_h, wl + IMG_WI, s, nl, quad);
            int col = s * 32 + nl; float bv = mb[col];
            #pragma unroll
            for (int r = 0; r < 4; ++r)
                sm.T1[sidx(Mt * 16 + quad * 4 + r, col)] = f2bf(c[r] + bv);
        }
        #pragma unroll
        for (int s = 0; s < 4; ++s) {
            f32x4 c = gemm_s(a_h, wl + IMG_WJ, s, nl, quad);
            int col = s * 32 + nl;
            #pragma unroll
            for (int r = 0; r < 4; ++r)
                sm.T2[sidx(Mt * 16 + quad * 4 + r, col)] = f2bf(c[r]);
        }
        __syncthreads();

        // D: msum — wave-local, in place in T1; jv/ev hoisted per g
        {
            float ccv[8];
            #pragma unroll
            for (int j = 0; j < 8; ++j)
                ccv[j] = (float)((double)(quad * 8 + j) * (5.0 / 19.0));
            #pragma unroll 1
            for (int g = 0; g < 16; ++g) {
                int n = g * 4 + Mt;
                int jv[4]; float ev[4];
                #pragma unroll
                for (int r = 0; r < 4; ++r) {
                    int k = quad * 4 + r;
                    jv[r] = sm.idx[n * 16 + k];
                    ev[r] = sm.env[n * 16 + k];
                }
                float ddm = sm.d[n * 16 + l15];
                short8 arb;
                #pragma unroll
                for (int j = 0; j < 8; ++j) {
                    float t2 = ddm - ccv[j];
                    float rv = __expf(-10.0f * t2 * t2);
                    arb[j] = (short)((quad * 8 + j) < 20 ? f2bf(rv) : (ushort_t)0);
                }
                #pragma unroll
                for (int s = 0; s < 4; ++s) {
                    short8 brw = *(const short8*)(wl + IMG_RW + s * 1024 + nl * 32 + quad * 8);
                    f32x4 c = {0.f, 0.f, 0.f, 0.f};
                    c = __builtin_amdgcn_mfma_f32_16x16x32_bf16(arb, brw, c, 0, 0, 0);
                    int col = s * 32 + nl;
                    float ai = bf2f(sm.T1[sidx(n, col)]);
                    float acc = 0.f;
                    #pragma unroll
                    for (int r = 0; r < 4; ++r) {
                        float gm = bf2f(sm.T2[sidx(jv[r], col)]);
                        acc = fmaf(siluf(ai + gm + c[r]), ev[r], acc);
                    }
                    acc += __shfl_xor(acc, 16);
                    acc += __shfl_xor(acc, 32);
                    if (quad == 0) sm.T1[sidx(n, col)] = f2bf(acc);
                }
            }
        }
        __syncthreads();

        // E: load a_m (msum)
        short8 a_m[4]; loadA(sm.T1, mrow, quad, a_m);
        __syncthreads();

        // F: UW(a_m)+Hf -> T2 local ; GS(rebuilt h)+gvec -> T1 glob
        #pragma unroll
        for (int s = 0; s < 4; ++s) {
            f32x4 c = gemm_s(a_m, wl + IMG_UW, s, nl, quad);
            int col = s * 32 + nl; float bv = ub[col];
            #pragma unroll
            for (int r = 0; r < 4; ++r) {
                int row = Mt * 16 + quad * 4 + r;
                sm.T2[sidx(row, col)] = f2bf(sm.Hf[row * HFS + col] + siluf(c[r] + bv));
            }
        }
        {
            short8 a_hh[4]; buildA(sm.Hf, mrow, quad, a_hh);
            #pragma unroll
            for (int s = 0; s < 4; ++s) {
                f32x4 c = gemm_s(a_hh, wl + IMG_GS, s, nl, quad);
                int col = s * 32 + nl; float gv = gvec[col];
                #pragma unroll
                for (int r = 0; r < 4; ++r)
                    sm.T1[sidx(Mt * 16 + quad * 4 + r, col)] = f2bf(siluf(c[r] + gv));
            }
        }
        __syncthreads();

        // G: fused = silu([local|glob]@[FT;FB]+fb) -> Hf, staged through Hf
        //    (old Hf is dead after F; each lane writes/reads only its own cells)
        {
            short8 a_t[4];
            loadA(sm.T2, mrow, quad, a_t);           // local
            #pragma unroll
            for (int s = 0; s < 4; ++s) {
                f32x4 c = gemm_s(a_t, wl + IMG_FT, s, nl, quad);
                int col = s * 32 + nl;
                int rb = (Mt * 16 + quad * 4) * HFS + col;
                sm.Hf[rb] = c[0]; sm.Hf[rb + HFS] = c[1];
                sm.Hf[rb + 2 * HFS] = c[2]; sm.Hf[rb + 3 * HFS] = c[3];
            }
            loadA(sm.T1, mrow, quad, a_t);           // glob
            float sr0 = 0.f, sr1 = 0.f, sr2 = 0.f, sr3 = 0.f;
            float qr0 = 0.f, qr1 = 0.f, qr2 = 0.f, qr3 = 0.f;
            #pragma unroll
            for (int s = 0; s < 4; ++s) {
                f32x4 c = gemm_s(a_t, wl + IMG_FB, s, nl, quad);
                int col = s * 32 + nl; float bv = fb[col];
                int rb = (Mt * 16 + quad * 4) * HFS + col;
                float v0 = siluf(sm.Hf[rb] + c[0] + bv);
                float v1 = siluf(sm.Hf[rb + HFS] + c[1] + bv);
                float v2 = siluf(sm.Hf[rb + 2 * HFS] + c[2] + bv);
                float v3 = siluf(sm.Hf[rb + 3 * HFS] + c[3] + bv);
                sm.Hf[rb] = v0; sm.Hf[rb + HFS] = v1;
                sm.Hf[rb + 2 * HFS] = v2; sm.Hf[rb + 3 * HFS] = v3;
                sr0 += v0; sr1 += v1; sr2 += v2; sr3 += v3;
                qr0 += v0 * v0; qr1 += v1 * v1; qr2 += v2 * v2; qr3 += v3 * v3;
            }
            #pragma unroll
            for (int o = 1; o < 16; o <<= 1) {
                sr0 += __shfl_xor(sr0, o); qr0 += __shfl_xor(qr0, o);
                sr1 += __shfl_xor(sr1, o); qr1 += __shfl_xor(qr1, o);
                sr2 += __shfl_xor(sr2, o); qr2 += __shfl_xor(qr2, o);
                sr3 += __shfl_xor(sr3, o); qr3 += __shfl_xor(qr3, o);
            }
            if (l15 == 0) {
                int base = (Mt * 16 + quad * 4) * 2 + (wave & 1);
                lnb[base]     = make_float2(sr0, qr0);
                lnb[base + 2] = make_float2(sr1, qr1);
                lnb[base + 4] = make_float2(sr2, qr2);
                lnb[base + 6] = make_float2(sr3, qr3);
            }
        }
        __syncthreads();

        // H: LN normalize (from Hf) -> T1 (x-hat)
        #pragma unroll
        for (int r = 0; r < 4; ++r) {
            int row = Mt * 16 + quad * 4 + r;
            float2 h0 = lnb[row * 2], h1 = lnb[row * 2 + 1];
            float mu = (h0.x + h1.x) * (1.0f / 128.0f);
            float var = (h0.y + h1.y) * (1.0f / 128.0f) - mu * mu;
            float rs = rsqrtf(var + 1e-5f);
            #pragma unroll
            for (int s = 0; s < 4; ++s) {
                int col = s * 32 + nl;
                sm.T1[sidx(row, col)] = f2bf((sm.Hf[row * HFS + col] - mu) * rs * lg[col] + lb[col]);
            }
        }
        __syncthreads();

        // J: Clifford MLP, 4 K-chunks; C1 stage in T2; C2 into register acc2
        {
            f32x4 acc2[4];
            #pragma unroll
            for (int s = 0; s < 4; ++s) acc2[s] = (f32x4){0.f, 0.f, 0.f, 0.f};
            #pragma unroll 1
            for (int j = 0; j < 4; ++j) {
                {
                    short8 a_x[4]; loadA(sm.T1, mrow, quad, a_x);   // x-hat (T1 intact all j)
                    #pragma unroll
                    for (int s = 0; s < 4; ++s) {
                        f32x4 c = gemm_s(a_x, wl + IMG_C1 + j * 16384, s, nl, quad);
                        int col = s * 32 + nl; float bv = c1b[j * H_ + col];
                        #pragma unroll
                        for (int r = 0; r < 4; ++r)
                            sm.T2[sidx(Mt * 16 + quad * 4 + r, col)] = f2bf(siluf(c[r] + bv));
                    }
                }
                __syncthreads();
                {
                    short8 a_t[4]; loadA(sm.T2, mrow, quad, a_t);
                    #pragma unroll
                    for (int s = 0; s < 4; ++s)
                        acc2[s] = gemm_s_acc(a_t, wl + IMG_C2 + j * 16384, s, nl, quad, acc2[s]);
                }
                __syncthreads();
            }

            // K: epilogue: h_next = fused(Hf) + acc2 + c2b -> Hf + T1 image
            #pragma unroll
            for (int s = 0; s < 4; ++s) {
                int col = s * 32 + nl; float bv = c2b[col];
                #pragma unroll
                for (int r = 0; r < 4; ++r) {
                    int row = Mt * 16 + quad * 4 + r;
                    float v = sm.Hf[row * HFS + col] + acc2[s][r] + bv;
                    sm.Hf[row * HFS + col] = v;
                    sm.T1[sidx(row, col)] = f2bf(v);
                }
            }
        }
        __syncthreads();
    }

    // ---- head ----
    {
        short8 a_f[4]; loadA(sm.T1, mrow, quad, a_f);
        #pragma unroll
        for (int s = 0; s < 4; ++s) {
            f32x4 c = gemm_s(a_f, wimg + IMG_FO, s, nl, quad);
            int col = s * 32 + nl; float bv = fo_b1[col];
            #pragma unroll
            for (int r = 0; r < 4; ++r)
                sm.T2[sidx(Mt * 16 + quad * 4 + r, col)] = f2bf(siluf(c[r] + bv));
        }
    }
    __syncthreads();
    if (tid < N_ * 3) {
        int n = tid / 3, j = tid - n * 3;
        float s = fo_b2[j];
        for (int c = 0; c < H_; ++c)
            s = fmaf(bf2f(sm.T2[sidx(n, c)]), fo_W2[c * 3 + j], s);
        out[b * N_ * 3 + tid] = s;
    }
}

extern "C" void kernel_launch(void* const* d_in, const int* in_sizes, int n_in,
                              void* d_out, int out_size, void* d_ws, size_t ws_size,
                              hipStream_t stream) {
    (void)in_sizes; (void)n_in; (void)out_size; (void)ws_size;
    convert_weights<<<248, 256, 0, stream>>>(
        (const float*)d_in[5], (const float*)d_in[7], (const float*)d_in[9],
        (const float*)d_in[12], (const float*)d_in[16], (const float*)d_in[18],
        (const float*)d_in[10], (const float*)d_in[20], (ushort_t*)d_ws);
    knn_kernel<<<B_, 64, 0, stream>>>((const float*)d_in[0], (char*)d_ws);
    md17_fused_kernel<<<B_, NT, 0, stream>>>(
        (const float*)d_in[0], (const int*)d_in[1],
        (const float*)d_in[2], (const float*)d_in[3], (const float*)d_in[4],
        (const float*)d_in[6], (const float*)d_in[8],
        (const float*)d_in[11], (const float*)d_in[13],
        (const float*)d_in[14], (const float*)d_in[15],
        (const float*)d_in[17], (const float*)d_in[19],
        (const float*)d_in[21],
        (const float*)d_in[22], (const float*)d_in[23],
        (char*)d_ws, (float*)d_out);
}

// Round 11
// 1478.779 us; speedup vs baseline: 1.1484x; 1.0073x over previous
//
#include <hip/hip_runtime.h>

typedef unsigned short ushort_t;
typedef unsigned int uint_t;
typedef unsigned long long ull_t;
typedef __attribute__((ext_vector_type(8))) short short8;
typedef __attribute__((ext_vector_type(4))) float f32x4;

#define B_ 1024
#define N_ 64
#define H_ 128
#define NT 256

// bf16 weight-image element offsets
#define IMG_WI 0
#define IMG_WJ 16384
#define IMG_UW 32768
#define IMG_GS 49152
#define IMG_FT 65536
#define IMG_FB 81920
#define IMG_C1 98304
#define IMG_C2 163840
#define IMG_GMT 229376
#define IMG_RW 245760
#define IMG_L 249856
#define IMG_FO 999424
#define WS_WEIGHTS (2u*1024u*1024u)
#define KNN_STRIDE 12288u

__device__ __forceinline__ ushort_t f2bf(float f) {
    uint_t u = __float_as_uint(f);
    return (ushort_t)((u + 0x7fffu + ((u >> 16) & 1u)) >> 16);
}
__device__ __forceinline__ float bf2f(ushort_t u) {
    union { uint_t i; float f; } v; v.i = ((uint_t)u) << 16; return v.f;
}
__device__ __forceinline__ float siluf(float x) { return x / (1.0f + __expf(-x)); }

// LDS swizzle: 16B-chunk c of row m stored at chunk c ^ (m&7)
__device__ __forceinline__ int sidx(int m, int k) {
    return m * H_ + (((k >> 3) ^ (m & 7)) << 3) + (k & 7);
}
__device__ __forceinline__ int fragoff(int m, int ch) {
    return m * H_ + ((ch ^ (m & 7)) << 3);
}

// ========== preamble 1: f32 weights -> transposed bf16 images ==============
extern "C" __global__ __launch_bounds__(256)
void convert_weights(const float* __restrict__ msg_W, const float* __restrict__ upd_W,
                     const float* __restrict__ gself_W, const float* __restrict__ fus_W,
                     const float* __restrict__ cb_W1, const float* __restrict__ cb_W2,
                     const float* __restrict__ gmean_W, const float* __restrict__ fo_W1,
                     ushort_t* __restrict__ wimg)
{
    const int g = blockIdx.x;
    if (g >= 244) {
        int st = g - 244;
        ushort_t* dst = wimg + IMG_FO + st * 4096;
        for (int e = 0; e < 16; ++e) {
            int q = threadIdx.x * 16 + e;
            int n = q >> 7, k = q & 127;
            dst[q] = f2bf(fo_W1[(size_t)k * 128 + st * 32 + n]);
        }
        return;
    }
    const int l = g / 61, r = g - l * 61;
    ushort_t* base = wimg + l * IMG_L;
    if (r == 60) {                       // rW pad image: 4 sub-stages [32f][32k]
        const float* W = msg_W + l * 35328 + 256 * 128;
        ushort_t* dst = base + IMG_RW;
        for (int e = 0; e < 16; ++e) {
            int q = threadIdx.x * 16 + e;
            int sub = q >> 10, n = (q >> 5) & 31, k = q & 31;
            dst[q] = f2bf(k < 20 ? W[(size_t)k * 128 + sub * 32 + n] : 0.0f);
        }
        return;
    }
    const float* W; int ld = 128, k0 = 0, c0, off, st;
    if      (r < 4)  { W = msg_W + l * 35328;            st = r;      off = IMG_WI;  c0 = st * 32; }
    else if (r < 8)  { W = msg_W + l * 35328;  k0 = 128; st = r - 4;  off = IMG_WJ;  c0 = st * 32; }
    else if (r < 12) { W = upd_W + l * 16384;            st = r - 8;  off = IMG_UW;  c0 = st * 32; }
    else if (r < 16) { W = gself_W + l * 16384;          st = r - 12; off = IMG_GS;  c0 = st * 32; }
    else if (r < 20) { W = fus_W + l * 32768;            st = r - 16; off = IMG_FT;  c0 = st * 32; }
    else if (r < 24) { W = fus_W + l * 32768;  k0 = 128; st = r - 20; off = IMG_FB;  c0 = st * 32; }
    else if (r < 40) { W = cb_W1 + l * 65536;  ld = 512; st = r - 24; off = IMG_C1;  c0 = st * 32; }
    else if (r < 56) { int j = (r - 40) >> 2; W = cb_W2 + l * 65536; k0 = j * 128;
                       st = r - 40; off = IMG_C2; c0 = ((r - 40) & 3) * 32; }
    else             { W = gmean_W + l * 16384;          st = r - 56; off = IMG_GMT; c0 = st * 32; }
    ushort_t* dst = base + off + st * 4096;
    for (int e = 0; e < 16; ++e) {
        int q = threadIdx.x * 16 + e;
        int n = q >> 7, k = q & 127;
        dst[q] = f2bf(W[(size_t)(k0 + k) * ld + c0 + n]);
    }
}

// ========== preamble 2: kNN per graph (1 wave), validated logic ============
extern "C" __global__ __launch_bounds__(64)
void knn_kernel(const float* __restrict__ positions, char* __restrict__ ws)
{
    const int b = blockIdx.x, lane = threadIdx.x;
    float px = positions[b * 192 + lane * 3 + 0];
    float py = positions[b * 192 + lane * 3 + 1];
    float pz = positions[b * 192 + lane * 3 + 2];
    float* kd = (float*)(ws + WS_WEIGHTS + (size_t)b * KNN_STRIDE);
    float* ke = kd + 1024;
    ushort_t* ki = (ushort_t*)(ke + 1024);
    for (int n = 0; n < 64; ++n) {
        float dx = __fsub_rn(__shfl(px, n), px);
        float dy = __fsub_rn(__shfl(py, n), py);
        float dz = __fsub_rn(__shfl(pz, n), pz);
        float d2 = __fadd_rn(__fadd_rn(__fmul_rn(dx, dx), __fmul_rn(dy, dy)), __fmul_rn(dz, dz));
        if (lane == n) d2 = 1e30f;
        float sd = 0.f; int si = 0;
        for (int k = 0; k < 16; ++k) {
            float dmin = d2;
            #pragma unroll
            for (int o = 1; o < 64; o <<= 1) dmin = fminf(dmin, __shfl_xor(dmin, o));
            ull_t mask = __ballot(d2 == dmin);
            int widx = __ffsll(mask) - 1;       // lowest index on ties (= top_k)
            if (lane == widx) d2 = 1e30f;
            if (lane == k) { si = widx; sd = dmin; }
        }
        if (lane < 16) {
            float dd = sqrtf(fmaxf(sd, 1e-12f));
            kd[n * 16 + lane] = dd;
            ke[n * 16 + lane] = (dd < 5.0f) ? 0.5f * (__cosf(0.62831853071795864769f * dd) + 1.0f) : 0.0f;
            ki[n * 16 + lane] = (ushort_t)si;
        }
    }
}

// ========== main fused kernel ==============================================
// 256 threads = 4 waves; wave w owns rows w*16..w*16+15 (ALL 128 cols).
// LDS: 16384*2 + 33792 + 4096 + 4096 + 2048 + 2048 = 78848 B -> 2 blocks/CU
#define HFS 132   // padded f32 row stride
struct __align__(16) Smem {
    ushort_t T1[N_ * H_];   // 16384B
    ushort_t T2[N_ * H_];   // 16384B
    float Hf[N_ * HFS];     // 33792B  f32 residual stream
    float d[1024];          //  4096B
    float env[1024];        //  4096B
    ushort_t idx[1024];     //  2048B
    char u[2048];           // union: spos(768) | {part bf16 1024, hmean 512, gvec 512}
};

// one output stage s (16 cols, col = s*16+l15), K=128: 4 B-frags from global
__device__ __forceinline__ f32x4 gemm_s(const short8 a[4], const ushort_t* __restrict__ img,
                                        int s, int l15, int quad)
{
    const ushort_t* base = img + ((s >> 1) << 12) + ((((s & 1) << 4) + l15) << 7) + quad * 8;
    short8 b0 = *(const short8*)(base);
    short8 b1 = *(const short8*)(base + 32);
    short8 b2 = *(const short8*)(base + 64);
    short8 b3 = *(const short8*)(base + 96);
    f32x4 c = {0.f, 0.f, 0.f, 0.f};
    c = __builtin_amdgcn_mfma_f32_16x16x32_bf16(a[0], b0, c, 0, 0, 0);
    c = __builtin_amdgcn_mfma_f32_16x16x32_bf16(a[1], b1, c, 0, 0, 0);
    c = __builtin_amdgcn_mfma_f32_16x16x32_bf16(a[2], b2, c, 0, 0, 0);
    c = __builtin_amdgcn_mfma_f32_16x16x32_bf16(a[3], b3, c, 0, 0, 0);
    return c;
}
__device__ __forceinline__ f32x4 gemm_s_acc(const short8 a[4], const ushort_t* __restrict__ img,
                                            int s, int l15, int quad, f32x4 c)
{
    const ushort_t* base = img + ((s >> 1) << 12) + ((((s & 1) << 4) + l15) << 7) + quad * 8;
    short8 b0 = *(const short8*)(base);
    short8 b1 = *(const short8*)(base + 32);
    short8 b2 = *(const short8*)(base + 64);
    short8 b3 = *(const short8*)(base + 96);
    c = __builtin_amdgcn_mfma_f32_16x16x32_bf16(a[0], b0, c, 0, 0, 0);
    c = __builtin_amdgcn_mfma_f32_16x16x32_bf16(a[1], b1, c, 0, 0, 0);
    c = __builtin_amdgcn_mfma_f32_16x16x32_bf16(a[2], b2, c, 0, 0, 0);
    c = __builtin_amdgcn_mfma_f32_16x16x32_bf16(a[3], b3, c, 0, 0, 0);
    return c;
}
__device__ __forceinline__ void loadA(const ushort_t* __restrict__ X, int mrow, int quad, short8 a[4]) {
    #pragma unroll
    for (int kc = 0; kc < 4; ++kc) a[kc] = *(const short8*)&X[fragoff(mrow, kc * 4 + quad)];
}
__device__ __forceinline__ void buildA(const float* __restrict__ Hf, int mrow, int quad, short8 a[4]) {
    #pragma unroll
    for (int kc = 0; kc < 4; ++kc) {
        const float* p = Hf + mrow * HFS + (kc * 4 + quad) * 8;
        float4 u0 = *(const float4*)p;
        float4 u1 = *(const float4*)(p + 4);
        short8 v;
        v[0] = (short)f2bf(u0.x); v[1] = (short)f2bf(u0.y);
        v[2] = (short)f2bf(u0.z); v[3] = (short)f2bf(u0.w);
        v[4] = (short)f2bf(u1.x); v[5] = (short)f2bf(u1.y);
        v[6] = (short)f2bf(u1.z); v[7] = (short)f2bf(u1.w);
        a[kc] = v;
    }
}

extern "C" __global__ __launch_bounds__(NT, 2)
void md17_fused_kernel(
    const float* __restrict__ positions, const int* __restrict__ atomic_numbers,
    const float* __restrict__ atom_embed, const float* __restrict__ pos_W,
    const float* __restrict__ pos_b,
    const float* __restrict__ msg_b, const float* __restrict__ upd_b,
    const float* __restrict__ g_b, const float* __restrict__ fus_b,
    const float* __restrict__ ln_g, const float* __restrict__ ln_b,
    const float* __restrict__ cb_b1, const float* __restrict__ cb_b2,
    const float* __restrict__ fo_b1,
    const float* __restrict__ fo_W2, const float* __restrict__ fo_b2,
    char* __restrict__ ws, float* __restrict__ out)
{
    __shared__ Smem sm;
    const int b = blockIdx.x;
    const int tid = threadIdx.x;
    const int wave = tid >> 6, lane = tid & 63;
    const int quad = lane >> 4, l15 = lane & 15;
    const int mrow = wave * 16 + l15;       // A-frag row (wave-owned)
    const int rbase = wave * 16 + quad * 4; // C-tile row base (wave-owned)

    const ushort_t* wimg = (const ushort_t*)ws;
    float* spos = (float*)sm.u;
    ushort_t* part = (ushort_t*)sm.u;       // [4][128] bf16 hmean partials
    float* hmean = (float*)(sm.u + 1024);
    float* gvec  = (float*)(sm.u + 1536);

    // ---- setup: kNN blob, positions, embeddings ----
    {
        const char* kb = ws + WS_WEIGHTS + (size_t)b * KNN_STRIDE;
        const float* kd = (const float*)kb;
        const float* ke = (const float*)(kb + 4096);
        const uint_t* ki = (const uint_t*)(kb + 8192);
        for (int t = tid; t < 1024; t += NT) { sm.d[t] = kd[t]; sm.env[t] = ke[t]; }
        for (int t = tid; t < 512; t += NT) ((uint_t*)sm.idx)[t] = ki[t];
        if (tid < 192) spos[tid] = positions[b * 192 + tid];
    }
    __syncthreads();
    for (int t = tid; t < N_ * H_; t += NT) {
        int n = t >> 7, f = t & 127;
        float v;
        if (f < 32) {
            v = atom_embed[atomic_numbers[b * N_ + n] * 32 + f];
        } else {
            int j = f - 32;
            v = pos_b[j];
            #pragma unroll
            for (int c = 0; c < 3; ++c)
                v = fmaf(spos[n * 3 + c], pos_W[c * 96 + j], v);
        }
        sm.Hf[n * HFS + f] = v;
        sm.T1[sidx(n, f)] = f2bf(v);
    }
    __syncthreads();

    #pragma unroll 1
    for (int l = 0; l < 4; ++l) {
        const ushort_t* wl = wimg + l * IMG_L;
        const float* mb  = msg_b + l * H_;
        const float* ub  = upd_b + l * H_;
        const float* gb  = g_b + l * H_;
        const float* fb  = fus_b + l * H_;
        const float* lg  = ln_g + l * H_;
        const float* lb  = ln_b + l * H_;
        const float* c1b = cb_b1 + l * 4 * H_;
        const float* c2b = cb_b2 + l * H_;

        // A: hmean partials over own 16 rows (from Hf)
        #pragma unroll
        for (int s = 0; s < 8; ++s) {
            int col = s * 16 + l15;
            const float* hp = sm.Hf + rbase * HFS + col;
            float p = hp[0] + hp[HFS] + hp[2 * HFS] + hp[3 * HFS];
            p += __shfl_xor(p, 16);
            p += __shfl_xor(p, 32);
            if (quad == 0) part[wave * 128 + col] = f2bf(p);
        }
        __syncthreads();                                 // B1
        if (tid < H_)
            hmean[tid] = (bf2f(part[tid]) + bf2f(part[128 + tid])
                        + bf2f(part[256 + tid]) + bf2f(part[384 + tid])) * (1.0f / 64.0f);
        __syncthreads();                                 // B2

        // C: gvec GEMV (waves 0-1) ; a_h ; WI -> T1 (+mb) ; WJ -> T2
        if (tid < H_) {
            float s = gb[tid];
            const ushort_t* wrow = wl + IMG_GMT + tid * 128;
            for (int c = 0; c < 128; c += 8) {
                short8 w = *(const short8*)(wrow + c);
                #pragma unroll
                for (int i = 0; i < 8; ++i) s = fmaf(hmean[c + i], bf2f((ushort_t)w[i]), s);
            }
            gvec[tid] = s;
        }
        {
            short8 a_h[4]; loadA(sm.T1, mrow, quad, a_h);   // h image, own rows
            #pragma unroll
            for (int s = 0; s < 8; ++s) {
                f32x4 c = gemm_s(a_h, wl + IMG_WI, s, l15, quad);
                int col = s * 16 + l15; float bv = mb[col];
                #pragma unroll
                for (int r = 0; r < 4; ++r)
                    sm.T1[sidx(rbase + r, col)] = f2bf(c[r] + bv);
            }
            #pragma unroll
            for (int s = 0; s < 8; ++s) {
                f32x4 c = gemm_s(a_h, wl + IMG_WJ, s, l15, quad);
                int col = s * 16 + l15;
                #pragma unroll
                for (int r = 0; r < 4; ++r)
                    sm.T2[sidx(rbase + r, col)] = f2bf(c[r]);
            }
        }
        __syncthreads();                                 // B3 (Gm visible to all)

        // D: msum — whole wave per atom n = wave*16+g (own rows), in place in T1
        {
            float ccv[8];
            #pragma unroll
            for (int j = 0; j < 8; ++j)
                ccv[j] = (float)((double)(quad * 8 + j) * (5.0 / 19.0));
            #pragma unroll 1
            for (int g = 0; g < 16; ++g) {
                int n = wave * 16 + g;
                int jv[4]; float ev[4];
                #pragma unroll
                for (int r = 0; r < 4; ++r) {
                    int k = quad * 4 + r;
                    jv[r] = sm.idx[n * 16 + k];
                    ev[r] = sm.env[n * 16 + k];
                }
                float ddm = sm.d[n * 16 + l15];
                short8 arb;
                #pragma unroll
                for (int j = 0; j < 8; ++j) {
                    float t2 = ddm - ccv[j];
                    float rv = __expf(-10.0f * t2 * t2);
                    arb[j] = (short)((quad * 8 + j) < 20 ? f2bf(rv) : (ushort_t)0);
                }
                #pragma unroll
                for (int s = 0; s < 8; ++s) {
                    int col = s * 16 + l15;
                    const ushort_t* rbase_p = wl + IMG_RW + ((s >> 1) << 10)
                                            + ((((s & 1) << 4) + l15) << 5) + quad * 8;
                    short8 brw = *(const short8*)rbase_p;
                    f32x4 c = {0.f, 0.f, 0.f, 0.f};
                    c = __builtin_amdgcn_mfma_f32_16x16x32_bf16(arb, brw, c, 0, 0, 0);
                    float ai = bf2f(sm.T1[sidx(n, col)]);
                    float acc = 0.f;
                    #pragma unroll
                    for (int r = 0; r < 4; ++r) {
                        float gm = bf2f(sm.T2[sidx(jv[r], col)]);
                        acc = fmaf(siluf(ai + gm + c[r]), ev[r], acc);
                    }
                    acc += __shfl_xor(acc, 16);
                    acc += __shfl_xor(acc, 32);
                    if (quad == 0) sm.T1[sidx(n, col)] = f2bf(acc);
                }
            }
        }
        __syncthreads();                                 // B4 (Gm reads done; T2 free)

        // ---- free-run region: everything below touches only own rows ----

        // F: UW(a_m)+Hf -> T2 local ; GS(rebuilt h)+gvec -> T1 glob
        {
            short8 a_m[4]; loadA(sm.T1, mrow, quad, a_m);
            #pragma unroll
            for (int s = 0; s < 8; ++s) {
                f32x4 c = gemm_s(a_m, wl + IMG_UW, s, l15, quad);
                int col = s * 16 + l15; float bv = ub[col];
                #pragma unroll
                for (int r = 0; r < 4; ++r)
                    sm.T2[sidx(rbase + r, col)] = f2bf(sm.Hf[(rbase + r) * HFS + col] + siluf(c[r] + bv));
            }
            short8 a_hh[4]; buildA(sm.Hf, mrow, quad, a_hh);
            #pragma unroll
            for (int s = 0; s < 8; ++s) {
                f32x4 c = gemm_s(a_hh, wl + IMG_GS, s, l15, quad);
                int col = s * 16 + l15; float gv = gvec[col];
                #pragma unroll
                for (int r = 0; r < 4; ++r)
                    sm.T1[sidx(rbase + r, col)] = f2bf(siluf(c[r] + gv));
            }
        }

        // G: fused = silu([local|glob]@[FT;FB]+fb) -> Hf ; LN sums in regs
        float sr[4] = {0.f, 0.f, 0.f, 0.f}, qr[4] = {0.f, 0.f, 0.f, 0.f};
        {
            short8 a_t[4];
            loadA(sm.T2, mrow, quad, a_t);               // local
            #pragma unroll
            for (int s = 0; s < 8; ++s) {
                f32x4 c = gemm_s(a_t, wl + IMG_FT, s, l15, quad);
                int col = s * 16 + l15;
                int rb = rbase * HFS + col;
                sm.Hf[rb] = c[0]; sm.Hf[rb + HFS] = c[1];
                sm.Hf[rb + 2 * HFS] = c[2]; sm.Hf[rb + 3 * HFS] = c[3];
            }
            loadA(sm.T1, mrow, quad, a_t);               // glob
            #pragma unroll
            for (int s = 0; s < 8; ++s) {
                f32x4 c = gemm_s(a_t, wl + IMG_FB, s, l15, quad);
                int col = s * 16 + l15; float bv = fb[col];
                int rb = rbase * HFS + col;
                #pragma unroll
                for (int r = 0; r < 4; ++r) {
                    float v = siluf(sm.Hf[rb + r * HFS] + c[r] + bv);
                    sm.Hf[rb + r * HFS] = v;
                    sr[r] += v; qr[r] += v * v;
                }
            }
            #pragma unroll
            for (int o = 1; o < 16; o <<= 1) {
                #pragma unroll
                for (int r = 0; r < 4; ++r) {
                    sr[r] += __shfl_xor(sr[r], o);
                    qr[r] += __shfl_xor(qr[r], o);
                }
            }
        }

        // H: LN normalize (wave-local) -> T1 (x-hat)
        #pragma unroll
        for (int r = 0; r < 4; ++r) {
            float mu = sr[r] * (1.0f / 128.0f);
            float var = qr[r] * (1.0f / 128.0f) - mu * mu;
            float rs = rsqrtf(var + 1e-5f);
            int row = rbase + r;
            #pragma unroll
            for (int s = 0; s < 8; ++s) {
                int col = s * 16 + l15;
                sm.T1[sidx(row, col)] = f2bf((sm.Hf[row * HFS + col] - mu) * rs * lg[col] + lb[col]);
            }
        }

        // J: Clifford MLP, 4 K-chunks; C1 -> T2; C2 -> register acc2 (no barriers)
        {
            short8 a_x[4]; loadA(sm.T1, mrow, quad, a_x);
            f32x4 acc2[8];
            #pragma unroll
            for (int s = 0; s < 8; ++s) acc2[s] = (f32x4){0.f, 0.f, 0.f, 0.f};
            #pragma unroll 1
            for (int j = 0; j < 4; ++j) {
                #pragma unroll
                for (int s = 0; s < 8; ++s) {
                    f32x4 c = gemm_s(a_x, wl + IMG_C1 + j * 16384, s, l15, quad);
                    int col = s * 16 + l15; float bv = c1b[j * H_ + col];
                    #pragma unroll
                    for (int r = 0; r < 4; ++r)
                        sm.T2[sidx(rbase + r, col)] = f2bf(siluf(c[r] + bv));
                }
                short8 a_t[4]; loadA(sm.T2, mrow, quad, a_t);
                #pragma unroll
                for (int s = 0; s < 8; ++s)
                    acc2[s] = gemm_s_acc(a_t, wl + IMG_C2 + j * 16384, s, l15, quad, acc2[s]);
            }
            // K: h_next = fused(Hf) + acc2 + c2b -> Hf + T1 image
            #pragma unroll
            for (int s = 0; s < 8; ++s) {
                int col = s * 16 + l15; float bv = c2b[col];
                #pragma unroll
                for (int r = 0; r < 4; ++r) {
                    int row = rbase + r;
                    float v = sm.Hf[row * HFS + col] + acc2[s][r] + bv;
                    sm.Hf[row * HFS + col] = v;
                    sm.T1[sidx(row, col)] = f2bf(v);
                }
            }
        }
        // no layer-end barrier: next stage A reads only own rows
    }

    // ---- head: FO -> T2 (own rows, no barrier) ; barrier ; gather -> out ----
    {
        short8 a_f[4]; loadA(sm.T1, mrow, quad, a_f);
        #pragma unroll
        for (int s = 0; s < 8; ++s) {
            f32x4 c = gemm_s(a_f, wimg + IMG_FO, s, l15, quad);
            int col = s * 16 + l15; float bv = fo_b1[col];
            #pragma unroll
            for (int r = 0; r < 4; ++r)
                sm.T2[sidx(rbase + r, col)] = f2bf(siluf(c[r] + bv));
        }
    }
    __syncthreads();
    if (tid < 192) {
        int n = tid / 3, j = tid - n * 3;
        float s = fo_b2[j];
        for (int c = 0; c < H_; ++c)
            s = fmaf(bf2f(sm.T2[sidx(n, c)]), fo_W2[c * 3 + j], s);
        out[b * 192 + tid] = s;
    }
}

extern "C" void kernel_launch(void* const* d_in, const int* in_sizes, int n_in,
                              void* d_out, int out_size, void* d_ws, size_t ws_size,
                              hipStream_t stream) {
    (void)in_sizes; (void)n_in; (void)out_size; (void)ws_size;
    convert_weights<<<248, 256, 0, stream>>>(
        (const float*)d_in[5], (const float*)d_in[7], (const float*)d_in[9],
        (const float*)d_in[12], (const float*)d_in[16], (const float*)d_in[18],
        (const float*)d_in[10], (const float*)d_in[20], (ushort_t*)d_ws);
    knn_kernel<<<B_, 64, 0, stream>>>((const float*)d_in[0], (char*)d_ws);
    md17_fused_kernel<<<B_, NT, 0, stream>>>(
        (const float*)d_in[0], (const int*)d_in[1],
        (const float*)d_in[2], (const float*)d_in[3], (const float*)d_in[4],
        (const float*)d_in[6], (const float*)d_in[8],
        (const float*)d_in[11], (const float*)d_in[13],
        (const float*)d_in[14], (const float*)d_in[15],
        (const float*)d_in[17], (const float*)d_in[19],
        (const float*)d_in[21],
        (const float*)d_in[22], (const float*)d_in[23],
        (char*)d_ws, (float*)d_out);
}